// Round 7
// baseline (101.241 us; speedup 1.0000x reference)
//
#include <hip/hip_runtime.h>
#include <hip/hip_bf16.h>
#include <math.h>

#define NN 4096
#define HH 256
#define G3 768
#define NHEADS 3
#define MAXE 128
#define ALPHA 0.2f

typedef __bf16 bf16;
typedef __attribute__((ext_vector_type(2))) __bf16 bf16x2;
typedef __attribute__((ext_vector_type(4))) __bf16 bf16x4;
typedef __attribute__((ext_vector_type(8))) __bf16 bf16x8;
typedef __attribute__((ext_vector_type(4))) float f32x4;

__device__ __forceinline__ void async_copy16(void* lds, const void* g) {
    __builtin_amdgcn_global_load_lds((const __attribute__((address_space(1))) void*)g,
                                     (__attribute__((address_space(3))) void*)lds, 16, 0, 0);
}

__device__ inline float lrelu(float x) { return x > 0.f ? x : ALPHA * x; }
__device__ inline float sigm(float x) { return 1.f / (1.f + __expf(-x)); }

// ================= prep: all converts + transposes + gat_c in one kernel =================
__global__ __launch_bounds__(256) void prep_k(
    const float* __restrict__ h,
    const float* __restrict__ eWih, const float* __restrict__ eWhh,
    const float* __restrict__ nWih, const float* __restrict__ nWhh,
    const float* __restrict__ gat_W, const float* __restrict__ gat_a,
    bf16* __restrict__ hb,
    bf16* __restrict__ Weib, bf16* __restrict__ Wehb,
    bf16* __restrict__ Wnib, bf16* __restrict__ Wnhb,
    bf16* __restrict__ Wtb, float* __restrict__ c0, float* __restrict__ c1) {
    __shared__ float tile[32][33];
    __shared__ float a_s[512];
    int b = blockIdx.x, t = threadIdx.x;
    if (b < 1024) {
        int idx = b * 256 + t;
        float4 v = *(const float4*)(h + (size_t)idx * 4);
        bf16x4 o = {(bf16)v.x, (bf16)v.y, (bf16)v.z, (bf16)v.w};
        *(bf16x4*)(hb + (size_t)idx * 4) = o;
    } else if (b < 1792) {
        int w = (b - 1024) / 192;
        int idx = ((b - 1024) % 192) * 256 + t;
        const float* in = w == 0 ? eWih : (w == 1 ? eWhh : (w == 2 ? nWih : nWhh));
        bf16* outp = w == 0 ? Weib : (w == 1 ? Wehb : (w == 2 ? Wnib : Wnhb));
        float4 v = *(const float4*)(in + (size_t)idx * 4);
        bf16x4 o = {(bf16)v.x, (bf16)v.y, (bf16)v.z, (bf16)v.w};
        *(bf16x4*)(outp + (size_t)idx * 4) = o;
    } else if (b < 1984) {
        int b2 = b - 1792;
        int hd = b2 >> 6, tl = b2 & 63;
        int k0 = (tl >> 3) * 32, n0 = (tl & 7) * 32;
        int tx = t % 32, ty = t / 32;
        const float* Wh = gat_W + (size_t)hd * HH * HH;
        for (int r = ty; r < 32; r += 8) tile[r][tx] = Wh[(size_t)(k0 + r) * HH + n0 + tx];
        __syncthreads();
        bf16* Wth = Wtb + (size_t)hd * HH * HH;
        for (int r = ty; r < 32; r += 8) Wth[(size_t)(n0 + r) * HH + k0 + tx] = (bf16)tile[tx][r];
    } else {
        int hd = b - 1984;
        a_s[t] = gat_a[(size_t)hd * 512 + t];
        a_s[t + 256] = gat_a[(size_t)hd * 512 + 256 + t];
        __syncthreads();
        const float* Wr = gat_W + (size_t)hd * HH * HH + (size_t)t * HH;
        f32x4 s0v = {}, s1v = {};
#pragma unroll 8
        for (int c4 = 0; c4 < 64; c4++) {
            f32x4 w = *(const f32x4*)(Wr + c4 * 4);
            f32x4 a0 = *(const f32x4*)(a_s + c4 * 4);
            f32x4 a1 = *(const f32x4*)(a_s + 256 + c4 * 4);
            s0v += w * a0;
            s1v += w * a1;
        }
        c0[hd * HH + t] = s0v[0] + s0v[1] + s0v[2] + s0v[3];
        c1[hd * HH + t] = s1v[0] + s1v[1] + s1v[2] + s1v[3];
    }
}

// ================= DMA-pipelined adjacency scan =================
// grid NN/2 blocks. Block owns rows {2b, 2b+1} of BOTH matrices = 4 tasks.
// Task tk: row = 2b + (tk>>1), matrix = tk&1 (0=node, 1=edge).
// DMA task tk+1 -> buf[(tk+1)&1] issued before processing task tk from buf[tk&1]:
// the 16 KB row stream overlaps compaction/gather (GEMM-style global_load_lds pipeline).
__global__ __launch_bounds__(256) void scan_k(
    const float* __restrict__ node_adj, const float* __restrict__ edge_adj,
    const bf16* __restrict__ hb,
    const float* __restrict__ c0, const float* __restrict__ c1,
    bf16* __restrict__ nsupb, float* __restrict__ dn, float* __restrict__ de,
    float* __restrict__ ep, float* __restrict__ em,
    int* __restrict__ csr_cols, int* __restrict__ csr_nnz) {
    __shared__ float buf[2][NN];      // 2 x 16 KB
    __shared__ int cnt[2];
    __shared__ int colsbuf[2][MAXE];
    __shared__ float part[6][4];
    int t = threadIdx.x, lane = t & 63, wid = t >> 6;
    int r0 = blockIdx.x * 2;

    if (t == 0) { cnt[0] = 0; cnt[1] = 0; }

    // issue DMA for task 0
    {
        const float* src = node_adj + (size_t)r0 * NN + t * 4;
        float* dst = &buf[0][t * 4];
#pragma unroll
        for (int q = 0; q < 4; q++) async_copy16(dst + q * 1024, src + q * 1024);
    }
    __syncthreads();  // drains DMA(0); orders cnt reset

#pragma unroll
    for (int tk = 0; tk < 4; tk++) {
        int par = tk & 1;
        int i = r0 + (tk >> 1);
        bool node_t = (par == 0);

        // issue DMA for next task (overlaps this task's processing)
        if (tk < 3) {
            int ntk = tk + 1;
            int nrow = r0 + (ntk >> 1);
            const float* src = ((ntk & 1) ? edge_adj : node_adj) + (size_t)nrow * NN + t * 4;
            float* dst = &buf[ntk & 1][t * 4];
#pragma unroll
            for (int q = 0; q < 4; q++) async_copy16(dst + q * 1024, src + q * 1024);
        }

        // ---- read my 16 elements (column-major: j = q*256 + t, bank-conflict-free) ----
        float wv[16];
#pragma unroll
        for (int q = 0; q < 16; q++) wv[q] = buf[par][q * 256 + t];

        // ---- two-pass compaction (no private arrays) ----
        int k = 0;
#pragma unroll
        for (int q = 0; q < 16; q++) {
            int j = q * 256 + t;
            if (wv[q] != 0.f) {
                if (j == i) (node_t ? dn : de)[i] = wv[q];
                else k++;
            }
        }
        int base = 0;
        if (k) base = atomicAdd(&cnt[par], k);
#pragma unroll
        for (int q = 0; q < 16; q++) {
            int j = q * 256 + t;
            if (wv[q] != 0.f && j != i) {
                if (base < MAXE) colsbuf[par][base] = (wv[q] > 0.f) ? (j + 1) : -(j + 1);
                base++;
            }
        }
        __syncthreads();  // compaction done (also drains next-task DMA — acceptable)
        int n = cnt[par];
        if (n > MAXE) n = MAXE;

        if (node_t) {
            // thread t owns h-column t
            float accp = 0.f, accm = 0.f;
#pragma unroll 8
            for (int kk = 0; kk < n; kk++) {
                int c = colsbuf[par][kk];  // LDS broadcast
                int j = (c > 0 ? c : -c) - 1;
                float hv = (float)hb[(size_t)j * HH + t];
                if (c > 0) accp += hv; else accm += hv;
            }
            nsupb[(size_t)i * HH + t] = (bf16)(accp - accm);
            // fused gat_e: 6 block-dot-products against c0/c1
            float u[6];
#pragma unroll
            for (int hd = 0; hd < NHEADS; hd++) {
                float a0 = c0[hd * HH + t], a1 = c1[hd * HH + t];
                u[hd * 2]     = accp * a0 + accm * a1;
                u[hd * 2 + 1] = accm * a0 + accp * a1;
            }
#pragma unroll
            for (int vv = 0; vv < 6; vv++)
#pragma unroll
                for (int off = 32; off; off >>= 1) u[vv] += __shfl_xor(u[vv], off);
            if (lane == 0)
#pragma unroll
                for (int vv = 0; vv < 6; vv++) part[vv][wid] = u[vv];
            __syncthreads();
            if (t < 6) {
                float s = part[t][0] + part[t][1] + part[t][2] + part[t][3];
                int hd = t >> 1;
                ((t & 1) == 0 ? ep : em)[(size_t)hd * NN + i] = lrelu(s);
            }
        } else {
            if (t == 0) csr_nnz[i] = n;
            if (t < n) csr_cols[(size_t)i * MAXE + t] = colsbuf[par][t];
        }
        __syncthreads();          // all reads of cnt/cols/part done
        if (t == 0) cnt[par] = 0; // ready for task tk+2 (ordered by tk+1's barriers)
    }
}

// ================= bf16 MFMA GEMM (m97 structure), z-batched up to 3 =================
__global__ __launch_bounds__(256) void gemm_bt(
    const bf16* __restrict__ A0, const bf16* __restrict__ A1, const bf16* __restrict__ A2,
    const bf16* __restrict__ B0, const bf16* __restrict__ B1, const bf16* __restrict__ B2,
    bf16* __restrict__ C0, bf16* __restrict__ C1, bf16* __restrict__ C2) {
    __shared__ bf16 a_s[128 * 32];
    __shared__ bf16 b_s[128 * 32];
    int z = blockIdx.z;
    const bf16* A = z == 0 ? A0 : (z == 1 ? A1 : A2);
    const bf16* Bt = z == 0 ? B0 : (z == 1 ? B1 : B2);
    bf16* C = z == 0 ? C0 : (z == 1 ? C1 : C2);

    int tid = threadIdx.x;
    int lane = tid & 63, wid = tid >> 6;
    int wr = (wid >> 1) * 64, wc = (wid & 1) * 64;
    int i0 = blockIdx.x * 128;
    int c0n = blockIdx.y * 128;

    f32x4 acc[4][4] = {};
    int kq = (lane >> 4) * 8;

    for (int k0 = 0; k0 < 256; k0 += 32) {
        __syncthreads();
#pragma unroll
        for (int it = 0; it < 2; it++) {
            int ch = it * 256 + tid;
            int r = ch >> 2, c16 = ch & 3;
            async_copy16(&a_s[ch * 8], A + (size_t)(i0 + r) * 256 + k0 + c16 * 8);
            async_copy16(&b_s[ch * 8], Bt + (size_t)(c0n + r) * 256 + k0 + c16 * 8);
        }
        __syncthreads();
        bf16x8 af[4], bf[4];
#pragma unroll
        for (int m = 0; m < 4; m++) af[m] = *(const bf16x8*)&a_s[(wr + m * 16 + (lane & 15)) * 32 + kq];
#pragma unroll
        for (int n = 0; n < 4; n++) bf[n] = *(const bf16x8*)&b_s[(wc + n * 16 + (lane & 15)) * 32 + kq];
#pragma unroll
        for (int m = 0; m < 4; m++)
#pragma unroll
            for (int n = 0; n < 4; n++)
                acc[m][n] = __builtin_amdgcn_mfma_f32_16x16x32_bf16(af[m], bf[n], acc[m][n], 0, 0, 0);
    }
#pragma unroll
    for (int m = 0; m < 4; m++) {
#pragma unroll
        for (int n = 0; n < 4; n++) {
            int row = i0 + wr + m * 16 + (lane >> 4) * 4;
            int col = c0n + wc + n * 16 + (lane & 15);
#pragma unroll
            for (int j = 0; j < 4; j++)
                C[(size_t)(row + j) * G3 + col] = (bf16)acc[m][n][j];
        }
    }
}

// ================= GAT sparse output =================
__global__ __launch_bounds__(256) void gat_out(
    const int* __restrict__ csr_cols, const int* __restrict__ csr_nnz,
    const float* __restrict__ ep, const float* __restrict__ em,
    const bf16* __restrict__ hWb2, bf16* __restrict__ esupb) {
    int i = blockIdx.x, t = threadIdx.x;
    __shared__ int cols_s[MAXE];
    __shared__ int js[MAXE];
    __shared__ float w_s[NHEADS][MAXE];
    __shared__ f32x4 sacc[NHEADS][64];
    int n = csr_nnz[i];
    if (t < n) {
        int c = csr_cols[(size_t)i * MAXE + t];
        cols_s[t] = c;
        js[t] = (c > 0 ? c : -c) - 1;
    }
    __syncthreads();
    int wid = t >> 6, lane = t & 63;
    if (wid < NHEADS) {
        int hd = wid;
        const float* eph = ep + (size_t)hd * NN;
        const float* emh = em + (size_t)hd * NN;
        float v0 = -1e30f, v1 = -1e30f;
        if (lane < n)      { int c = cols_s[lane];      v0 = c > 0 ? eph[js[lane]]      : emh[js[lane]]; }
        if (lane + 64 < n) { int c = cols_s[lane + 64]; v1 = c > 0 ? eph[js[lane + 64]] : emh[js[lane + 64]]; }
        float mx = fmaxf(v0, v1);
#pragma unroll
        for (int off = 32; off; off >>= 1) mx = fmaxf(mx, __shfl_xor(mx, off));
        float w0 = (lane < n) ? __expf(v0 - mx) : 0.f;
        float w1 = (lane + 64 < n) ? __expf(v1 - mx) : 0.f;
        float s = w0 + w1;
#pragma unroll
        for (int off = 32; off; off >>= 1) s += __shfl_xor(s, off);
        float inv = 1.f / s;
        if (lane < n)      w_s[hd][lane]      = (cols_s[lane] > 0 ? w0 : -w0) * inv;
        if (lane + 64 < n) w_s[hd][lane + 64] = (cols_s[lane + 64] > 0 ? w1 : -w1) * inv;
    }
    __syncthreads();
    if (t < 192) {
        int hd = t >> 6, g = t & 63;
        const bf16* base = hWb2 + (size_t)hd * HH + g * 4;
        f32x4 acc = {};
#pragma unroll 4
        for (int k = 0; k < n; k++) {
            float w = w_s[hd][k];
            bf16x4 hv = *(const bf16x4*)(base + (size_t)js[k] * G3);
            f32x4 f = {(float)hv[0], (float)hv[1], (float)hv[2], (float)hv[3]};
            acc += w * f;
        }
        sacc[hd][g] = acc;
    }
    __syncthreads();
    if (t < 64) {
        f32x4 s = (sacc[0][t] + sacc[1][t] + sacc[2][t]) * (1.f / 3.f);
        bf16x4 o = {(bf16)s[0], (bf16)s[1], (bf16)s[2], (bf16)s[3]};
        *(bf16x4*)(esupb + (size_t)i * HH + t * 4) = o;
    }
}

// ================= both GRU cells + final combine, writes d_out =================
__global__ __launch_bounds__(256) void gru_both(
    const bf16* __restrict__ gie, const bf16* __restrict__ ghe,
    const bf16* __restrict__ gin, const bf16* __restrict__ ghn,
    const float* __restrict__ ebih, const float* __restrict__ ebhh,
    const float* __restrict__ nbih, const float* __restrict__ nbhh,
    const float* __restrict__ h, const float* __restrict__ dnv, const float* __restrict__ dev,
    float* __restrict__ out) {
    int sub = threadIdx.x >> 7, tc = threadIdx.x & 127;
    int i = blockIdx.x * 2 + sub;
    int c = tc * 2;
    size_t gb = (size_t)i * G3;
    float2 hv = *(const float2*)(h + (size_t)i * HH + c);
    float De = dev[i], Dn = dnv[i];

#define LD2(p, off) (*(const bf16x2*)((p) + gb + (off) + c))
#define BI2(p, off) (*(const float2*)((p) + (off) + c))
    bf16x2 eir = LD2(gie, 0), eiz = LD2(gie, 256), ein = LD2(gie, 512);
    bf16x2 ehr = LD2(ghe, 0), ehz = LD2(ghe, 256), ehn = LD2(ghe, 512);
    bf16x2 nir = LD2(gin, 0), niz = LD2(gin, 256), nin = LD2(gin, 512);
    bf16x2 nhr = LD2(ghn, 0), nhz = LD2(ghn, 256), nhn = LD2(ghn, 512);
    float2 ebr = BI2(ebih, 0), ebz = BI2(ebih, 256), ebn = BI2(ebih, 512);
    float2 eb2r = BI2(ebhh, 0), eb2z = BI2(ebhh, 256), eb2n = BI2(ebhh, 512);
    float2 nbr = BI2(nbih, 0), nbz = BI2(nbih, 256), nbn = BI2(nbih, 512);
    float2 nb2r = BI2(nbhh, 0), nb2z = BI2(nbhh, 256), nb2n = BI2(nbhh, 512);
#undef LD2
#undef BI2

    float res[2];
#pragma unroll
    for (int j = 0; j < 2; j++) {
        float hj = j == 0 ? hv.x : hv.y;
        float r = sigm(((float)eir[j] + (j ? ebr.y : ebr.x)) + ((float)ehr[j] + (j ? eb2r.y : eb2r.x)));
        float z = sigm(((float)eiz[j] + (j ? ebz.y : ebz.x)) + ((float)ehz[j] + (j ? eb2z.y : eb2z.x)));
        float nv = tanhf(((float)ein[j] + (j ? ebn.y : ebn.x)) + r * ((float)ehn[j] + (j ? eb2n.y : eb2n.x)));
        float eo = (1.f - z) * nv + z * hj;
        float r2 = sigm(((float)nir[j] + (j ? nbr.y : nbr.x)) + ((float)nhr[j] + (j ? nb2r.y : nb2r.x)));
        float z2 = sigm(((float)niz[j] + (j ? nbz.y : nbz.x)) + ((float)nhz[j] + (j ? nb2z.y : nb2z.x)));
        float nv2 = tanhf(((float)nin[j] + (j ? nbn.y : nbn.x)) + r2 * ((float)nhn[j] + (j ? nb2n.y : nb2n.x)));
        float no = (1.f - z2) * nv2 + z2 * hj;
        res[j] = De * eo + Dn * no;
    }
    *(float2*)(out + (size_t)i * HH + c) = make_float2(res[0], res[1]);
}

extern "C" void kernel_launch(void* const* d_in, const int* in_sizes, int n_in,
                              void* d_out, int out_size, void* d_ws, size_t ws_size,
                              hipStream_t stream) {
    const float* h        = (const float*)d_in[0];
    const float* node_adj = (const float*)d_in[1];
    const float* edge_adj = (const float*)d_in[2];
    const float* gat_W    = (const float*)d_in[3];
    const float* gat_a    = (const float*)d_in[4];
    const float* e_Wih    = (const float*)d_in[5];
    const float* e_Whh    = (const float*)d_in[6];
    const float* e_bih    = (const float*)d_in[7];
    const float* e_bhh    = (const float*)d_in[8];
    const float* n_Wih    = (const float*)d_in[9];
    const float* n_Whh    = (const float*)d_in[10];
    const float* n_bih    = (const float*)d_in[11];
    const float* n_bhh    = (const float*)d_in[12];
    float* out = (float*)d_out;

    char* ws = (char*)d_ws;
    size_t off = 0;
    auto alloc = [&](size_t bytes) { char* p = ws + off; off += (bytes + 255) & ~(size_t)255; return p; };

    float* ep    = (float*)alloc((size_t)NHEADS * NN * 4);
    float* em    = (float*)alloc((size_t)NHEADS * NN * 4);
    float* c0    = (float*)alloc((size_t)NHEADS * HH * 4);
    float* c1    = (float*)alloc((size_t)NHEADS * HH * 4);
    float* dn    = (float*)alloc(NN * 4);
    float* de    = (float*)alloc(NN * 4);
    bf16*  hb    = (bf16*)alloc((size_t)NN * HH * 2);
    bf16*  nsupb = (bf16*)alloc((size_t)NN * HH * 2);
    bf16*  esupb = (bf16*)alloc((size_t)NN * HH * 2);
    bf16*  hWb2  = (bf16*)alloc((size_t)NN * G3 * 2);
    bf16*  gie   = (bf16*)alloc((size_t)NN * G3 * 2);
    bf16*  ghe   = (bf16*)alloc((size_t)NN * G3 * 2);
    bf16*  gin   = (bf16*)alloc((size_t)NN * G3 * 2);
    bf16*  ghn   = (bf16*)alloc((size_t)NN * G3 * 2);
    bf16*  Weib  = (bf16*)alloc((size_t)G3 * HH * 2);
    bf16*  Wehb  = (bf16*)alloc((size_t)G3 * HH * 2);
    bf16*  Wnib  = (bf16*)alloc((size_t)G3 * HH * 2);
    bf16*  Wnhb  = (bf16*)alloc((size_t)G3 * HH * 2);
    bf16*  Wtb   = (bf16*)alloc((size_t)NHEADS * HH * HH * 2);
    int*   csr_cols = (int*)alloc((size_t)NN * MAXE * 4);
    int*   csr_nnz  = (int*)alloc(NN * 4);

    dim3 b256(256);

    // 1. prep: converts + gat_W transpose + gat_c
    prep_k<<<1987, b256, 0, stream>>>(h, e_Wih, e_Whh, n_Wih, n_Whh, gat_W, gat_a,
                                      hb, Weib, Wehb, Wnib, Wnhb, Wtb, c0, c1);

    // 2. DMA-pipelined scans (node: gather+nsup+gat_e fused; edge: CSR)
    scan_k<<<NN / 2, b256, 0, stream>>>(node_adj, edge_adj, hb, c0, c1,
                                        nsupb, dn, de, ep, em, csr_cols, csr_nnz);

    // 3. gemmA z=3: hW (3 heads concat N=768), gi_e, gh_e
    gemm_bt<<<dim3(NN / 128, G3 / 128, 3), b256, 0, stream>>>(
        hb, nsupb, hb, Wtb, Weib, Wehb, hWb2, gie, ghe);

    // 4. GAT sparse attention output
    gat_out<<<NN, b256, 0, stream>>>(csr_cols, csr_nnz, ep, em, hWb2, esupb);

    // 5. gemmB z=2: gi_n, gh_n
    gemm_bt<<<dim3(NN / 128, G3 / 128, 2), b256, 0, stream>>>(
        esupb, hb, hb, Wnib, Wnhb, Wnhb, gin, ghn, ghn);

    // 6. both GRUs + combine -> out
    gru_both<<<NN / 2, b256, 0, stream>>>(gie, ghe, gin, ghn,
                                          e_bih, e_bhh, n_bih, n_bhh,
                                          h, dn, de, out);
}

// Round 8
// 95.425 us; speedup vs baseline: 1.0609x; 1.0609x over previous
//
#include <hip/hip_runtime.h>
#include <hip/hip_bf16.h>
#include <math.h>

#define NN 4096
#define HH 256
#define G3 768
#define NHEADS 3
#define MAXE 128
#define ALPHA 0.2f

typedef __bf16 bf16;
typedef __attribute__((ext_vector_type(2))) __bf16 bf16x2;
typedef __attribute__((ext_vector_type(4))) __bf16 bf16x4;
typedef __attribute__((ext_vector_type(8))) __bf16 bf16x8;
typedef __attribute__((ext_vector_type(4))) float f32x4;

__device__ __forceinline__ void async_copy16(void* lds, const void* g) {
    __builtin_amdgcn_global_load_lds((const __attribute__((address_space(1))) void*)g,
                                     (__attribute__((address_space(3))) void*)lds, 16, 0, 0);
}

__device__ inline float lrelu(float x) { return x > 0.f ? x : ALPHA * x; }
__device__ inline float sigm(float x) { return 1.f / (1.f + __expf(-x)); }

// ================= prep: all converts + transposes + gat_c in one kernel =================
__global__ __launch_bounds__(256) void prep_k(
    const float* __restrict__ h,
    const float* __restrict__ eWih, const float* __restrict__ eWhh,
    const float* __restrict__ nWih, const float* __restrict__ nWhh,
    const float* __restrict__ gat_W, const float* __restrict__ gat_a,
    bf16* __restrict__ hb,
    bf16* __restrict__ Weib, bf16* __restrict__ Wehb,
    bf16* __restrict__ Wnib, bf16* __restrict__ Wnhb,
    bf16* __restrict__ Wtb, float* __restrict__ c0, float* __restrict__ c1) {
    __shared__ float tile[32][33];
    __shared__ float a_s[512];
    int b = blockIdx.x, t = threadIdx.x;
    if (b < 1024) {
        int idx = b * 256 + t;
        float4 v = *(const float4*)(h + (size_t)idx * 4);
        bf16x4 o = {(bf16)v.x, (bf16)v.y, (bf16)v.z, (bf16)v.w};
        *(bf16x4*)(hb + (size_t)idx * 4) = o;
    } else if (b < 1792) {
        int w = (b - 1024) / 192;
        int idx = ((b - 1024) % 192) * 256 + t;
        const float* in = w == 0 ? eWih : (w == 1 ? eWhh : (w == 2 ? nWih : nWhh));
        bf16* outp = w == 0 ? Weib : (w == 1 ? Wehb : (w == 2 ? Wnib : Wnhb));
        float4 v = *(const float4*)(in + (size_t)idx * 4);
        bf16x4 o = {(bf16)v.x, (bf16)v.y, (bf16)v.z, (bf16)v.w};
        *(bf16x4*)(outp + (size_t)idx * 4) = o;
    } else if (b < 1984) {
        int b2 = b - 1792;
        int hd = b2 >> 6, tl = b2 & 63;
        int k0 = (tl >> 3) * 32, n0 = (tl & 7) * 32;
        int tx = t % 32, ty = t / 32;
        const float* Wh = gat_W + (size_t)hd * HH * HH;
        for (int r = ty; r < 32; r += 8) tile[r][tx] = Wh[(size_t)(k0 + r) * HH + n0 + tx];
        __syncthreads();
        bf16* Wth = Wtb + (size_t)hd * HH * HH;
        for (int r = ty; r < 32; r += 8) Wth[(size_t)(n0 + r) * HH + k0 + tx] = (bf16)tile[tx][r];
    } else {
        int hd = b - 1984;
        a_s[t] = gat_a[(size_t)hd * 512 + t];
        a_s[t + 256] = gat_a[(size_t)hd * 512 + 256 + t];
        __syncthreads();
        const float* Wr = gat_W + (size_t)hd * HH * HH + (size_t)t * HH;
        f32x4 s0v = {}, s1v = {};
#pragma unroll 8
        for (int c4 = 0; c4 < 64; c4++) {
            f32x4 w = *(const f32x4*)(Wr + c4 * 4);
            f32x4 a0 = *(const f32x4*)(a_s + c4 * 4);
            f32x4 a1 = *(const f32x4*)(a_s + 256 + c4 * 4);
            s0v += w * a0;
            s1v += w * a1;
        }
        c0[hd * HH + t] = s0v[0] + s0v[1] + s0v[2] + s0v[3];
        c1[hd * HH + t] = s1v[0] + s1v[1] + s1v[2] + s1v[3];
    }
}

// ================= pure streaming compaction =================
// 8192 blocks: b < NN -> node row b; else edge row b-NN. Block = exactly one row
// (256 threads x 16 elems). No gather tail: waves retire fast, loads stay in flight.
__global__ __launch_bounds__(256) void compact_k(
    const float* __restrict__ node_adj, const float* __restrict__ edge_adj,
    float* __restrict__ dn, float* __restrict__ de,
    int* __restrict__ ccols_n, int* __restrict__ nnz_n,
    int* __restrict__ ccols_e, int* __restrict__ nnz_e) {
    int b = blockIdx.x, t = threadIdx.x;
    bool node = b < NN;
    int i = node ? b : b - NN;
    __shared__ int cnt;
    __shared__ int cols_s[MAXE];
    if (t == 0) cnt = 0;
    __syncthreads();
    const float* rp = (node ? node_adj : edge_adj) + (size_t)i * NN + t * 16;

    // 4 independent 16-B loads (named registers)
    f32x4 v0 = *(const f32x4*)(rp);
    f32x4 v1 = *(const f32x4*)(rp + 4);
    f32x4 v2 = *(const f32x4*)(rp + 8);
    f32x4 v3 = *(const f32x4*)(rp + 12);
    int j0 = t * 16;

    // pass 1: count (diag excluded; diag -> dn/de)
    int k = 0;
#define CNT(A, J) { float a_ = (A); if (a_ != 0.f) { if ((J) == i) (node ? dn : de)[i] = a_; else k++; } }
    CNT(v0[0], j0)      CNT(v0[1], j0 + 1)  CNT(v0[2], j0 + 2)  CNT(v0[3], j0 + 3)
    CNT(v1[0], j0 + 4)  CNT(v1[1], j0 + 5)  CNT(v1[2], j0 + 6)  CNT(v1[3], j0 + 7)
    CNT(v2[0], j0 + 8)  CNT(v2[1], j0 + 9)  CNT(v2[2], j0 + 10) CNT(v2[3], j0 + 11)
    CNT(v3[0], j0 + 12) CNT(v3[1], j0 + 13) CNT(v3[2], j0 + 14) CNT(v3[3], j0 + 15)
#undef CNT

    int base = 0;
    if (k) base = atomicAdd(&cnt, k);

    // pass 2: write
#define WRT(A, J) { float a_ = (A); if (a_ != 0.f && (J) != i) { \
        if (base < MAXE) cols_s[base] = (a_ > 0.f) ? ((J) + 1) : -((J) + 1); base++; } }
    WRT(v0[0], j0)      WRT(v0[1], j0 + 1)  WRT(v0[2], j0 + 2)  WRT(v0[3], j0 + 3)
    WRT(v1[0], j0 + 4)  WRT(v1[1], j0 + 5)  WRT(v1[2], j0 + 6)  WRT(v1[3], j0 + 7)
    WRT(v2[0], j0 + 8)  WRT(v2[1], j0 + 9)  WRT(v2[2], j0 + 10) WRT(v2[3], j0 + 11)
    WRT(v3[0], j0 + 12) WRT(v3[1], j0 + 13) WRT(v3[2], j0 + 14) WRT(v3[3], j0 + 15)
#undef WRT

    __syncthreads();
    int n = cnt < MAXE ? cnt : MAXE;
    int* cg = (node ? ccols_n : ccols_e) + (size_t)i * MAXE;
    if (t == 0) (node ? nnz_n : nnz_e)[i] = n;
    if (t < n) cg[t] = cols_s[t];
}

// ================= node gather: nsup + fused gat_e (reads node CSR) =================
__global__ __launch_bounds__(256) void gather_k(
    const int* __restrict__ ccols_n, const int* __restrict__ nnz_n,
    const bf16* __restrict__ hb,
    const float* __restrict__ c0, const float* __restrict__ c1,
    bf16* __restrict__ nsupb, float* __restrict__ ep, float* __restrict__ em) {
    int i = blockIdx.x, t = threadIdx.x, lane = t & 63, wid = t >> 6;
    __shared__ int cols_s[MAXE];
    __shared__ float part[6][4];
    int n = nnz_n[i];
    if (n > MAXE) n = MAXE;
    if (t < n) cols_s[t] = ccols_n[(size_t)i * MAXE + t];
    __syncthreads();
    float accp = 0.f, accm = 0.f;
#pragma unroll 8
    for (int kk = 0; kk < n; kk++) {
        int c = cols_s[kk];  // LDS broadcast
        int j = (c > 0 ? c : -c) - 1;
        float hv = (float)hb[(size_t)j * HH + t];
        if (c > 0) accp += hv; else accm += hv;
    }
    nsupb[(size_t)i * HH + t] = (bf16)(accp - accm);
    // fused gat_e: 6 block-dot-products against c0/c1
    float u[6];
#pragma unroll
    for (int hd = 0; hd < NHEADS; hd++) {
        float a0 = c0[hd * HH + t], a1 = c1[hd * HH + t];
        u[hd * 2]     = accp * a0 + accm * a1;
        u[hd * 2 + 1] = accm * a0 + accp * a1;
    }
#pragma unroll
    for (int vv = 0; vv < 6; vv++)
#pragma unroll
        for (int off = 32; off; off >>= 1) u[vv] += __shfl_xor(u[vv], off);
    if (lane == 0)
#pragma unroll
        for (int vv = 0; vv < 6; vv++) part[vv][wid] = u[vv];
    __syncthreads();
    if (t < 6) {
        float s = part[t][0] + part[t][1] + part[t][2] + part[t][3];
        int hd = t >> 1;
        ((t & 1) == 0 ? ep : em)[(size_t)hd * NN + i] = lrelu(s);
    }
}

// ================= bf16 MFMA GEMM (m97 structure), z-batched up to 3 =================
__global__ __launch_bounds__(256) void gemm_bt(
    const bf16* __restrict__ A0, const bf16* __restrict__ A1, const bf16* __restrict__ A2,
    const bf16* __restrict__ B0, const bf16* __restrict__ B1, const bf16* __restrict__ B2,
    bf16* __restrict__ C0, bf16* __restrict__ C1, bf16* __restrict__ C2) {
    __shared__ bf16 a_s[128 * 32];
    __shared__ bf16 b_s[128 * 32];
    int z = blockIdx.z;
    const bf16* A = z == 0 ? A0 : (z == 1 ? A1 : A2);
    const bf16* Bt = z == 0 ? B0 : (z == 1 ? B1 : B2);
    bf16* C = z == 0 ? C0 : (z == 1 ? C1 : C2);

    int tid = threadIdx.x;
    int lane = tid & 63, wid = tid >> 6;
    int wr = (wid >> 1) * 64, wc = (wid & 1) * 64;
    int i0 = blockIdx.x * 128;
    int c0n = blockIdx.y * 128;

    f32x4 acc[4][4] = {};
    int kq = (lane >> 4) * 8;

    for (int k0 = 0; k0 < 256; k0 += 32) {
        __syncthreads();
#pragma unroll
        for (int it = 0; it < 2; it++) {
            int ch = it * 256 + tid;
            int r = ch >> 2, c16 = ch & 3;
            async_copy16(&a_s[ch * 8], A + (size_t)(i0 + r) * 256 + k0 + c16 * 8);
            async_copy16(&b_s[ch * 8], Bt + (size_t)(c0n + r) * 256 + k0 + c16 * 8);
        }
        __syncthreads();
        bf16x8 af[4], bf[4];
#pragma unroll
        for (int m = 0; m < 4; m++) af[m] = *(const bf16x8*)&a_s[(wr + m * 16 + (lane & 15)) * 32 + kq];
#pragma unroll
        for (int n = 0; n < 4; n++) bf[n] = *(const bf16x8*)&b_s[(wc + n * 16 + (lane & 15)) * 32 + kq];
#pragma unroll
        for (int m = 0; m < 4; m++)
#pragma unroll
            for (int n = 0; n < 4; n++)
                acc[m][n] = __builtin_amdgcn_mfma_f32_16x16x32_bf16(af[m], bf[n], acc[m][n], 0, 0, 0);
    }
#pragma unroll
    for (int m = 0; m < 4; m++) {
#pragma unroll
        for (int n = 0; n < 4; n++) {
            int row = i0 + wr + m * 16 + (lane >> 4) * 4;
            int col = c0n + wc + n * 16 + (lane & 15);
#pragma unroll
            for (int j = 0; j < 4; j++)
                C[(size_t)(row + j) * G3 + col] = (bf16)acc[m][n][j];
        }
    }
}

// ================= GAT sparse output =================
__global__ __launch_bounds__(256) void gat_out(
    const int* __restrict__ ccols_e, const int* __restrict__ nnz_e,
    const float* __restrict__ ep, const float* __restrict__ em,
    const bf16* __restrict__ hWb2, bf16* __restrict__ esupb) {
    int i = blockIdx.x, t = threadIdx.x;
    __shared__ int cols_s[MAXE];
    __shared__ int js[MAXE];
    __shared__ float w_s[NHEADS][MAXE];
    __shared__ f32x4 sacc[NHEADS][64];
    int n = nnz_e[i];
    if (n > MAXE) n = MAXE;
    if (t < n) {
        int c = ccols_e[(size_t)i * MAXE + t];
        cols_s[t] = c;
        js[t] = (c > 0 ? c : -c) - 1;
    }
    __syncthreads();
    int wid = t >> 6, lane = t & 63;
    if (wid < NHEADS) {
        int hd = wid;
        const float* eph = ep + (size_t)hd * NN;
        const float* emh = em + (size_t)hd * NN;
        float v0 = -1e30f, v1 = -1e30f;
        if (lane < n)      { int c = cols_s[lane];      v0 = c > 0 ? eph[js[lane]]      : emh[js[lane]]; }
        if (lane + 64 < n) { int c = cols_s[lane + 64]; v1 = c > 0 ? eph[js[lane + 64]] : emh[js[lane + 64]]; }
        float mx = fmaxf(v0, v1);
#pragma unroll
        for (int off = 32; off; off >>= 1) mx = fmaxf(mx, __shfl_xor(mx, off));
        float w0 = (lane < n) ? __expf(v0 - mx) : 0.f;
        float w1 = (lane + 64 < n) ? __expf(v1 - mx) : 0.f;
        float s = w0 + w1;
#pragma unroll
        for (int off = 32; off; off >>= 1) s += __shfl_xor(s, off);
        float inv = 1.f / s;
        if (lane < n)      w_s[hd][lane]      = (cols_s[lane] > 0 ? w0 : -w0) * inv;
        if (lane + 64 < n) w_s[hd][lane + 64] = (cols_s[lane + 64] > 0 ? w1 : -w1) * inv;
    }
    __syncthreads();
    if (t < 192) {
        int hd = t >> 6, g = t & 63;
        const bf16* base = hWb2 + (size_t)hd * HH + g * 4;
        f32x4 acc = {};
#pragma unroll 4
        for (int k = 0; k < n; k++) {
            float w = w_s[hd][k];
            bf16x4 hv = *(const bf16x4*)(base + (size_t)js[k] * G3);
            f32x4 f = {(float)hv[0], (float)hv[1], (float)hv[2], (float)hv[3]};
            acc += w * f;
        }
        sacc[hd][g] = acc;
    }
    __syncthreads();
    if (t < 64) {
        f32x4 s = (sacc[0][t] + sacc[1][t] + sacc[2][t]) * (1.f / 3.f);
        bf16x4 o = {(bf16)s[0], (bf16)s[1], (bf16)s[2], (bf16)s[3]};
        *(bf16x4*)(esupb + (size_t)i * HH + t * 4) = o;
    }
}

// ================= both GRU cells + final combine, writes d_out =================
__global__ __launch_bounds__(256) void gru_both(
    const bf16* __restrict__ gie, const bf16* __restrict__ ghe,
    const bf16* __restrict__ gin, const bf16* __restrict__ ghn,
    const float* __restrict__ ebih, const float* __restrict__ ebhh,
    const float* __restrict__ nbih, const float* __restrict__ nbhh,
    const float* __restrict__ h, const float* __restrict__ dnv, const float* __restrict__ dev,
    float* __restrict__ out) {
    int sub = threadIdx.x >> 7, tc = threadIdx.x & 127;
    int i = blockIdx.x * 2 + sub;
    int c = tc * 2;
    size_t gb = (size_t)i * G3;
    float2 hv = *(const float2*)(h + (size_t)i * HH + c);
    float De = dev[i], Dn = dnv[i];

#define LD2(p, off) (*(const bf16x2*)((p) + gb + (off) + c))
#define BI2(p, off) (*(const float2*)((p) + (off) + c))
    bf16x2 eir = LD2(gie, 0), eiz = LD2(gie, 256), ein = LD2(gie, 512);
    bf16x2 ehr = LD2(ghe, 0), ehz = LD2(ghe, 256), ehn = LD2(ghe, 512);
    bf16x2 nir = LD2(gin, 0), niz = LD2(gin, 256), nin = LD2(gin, 512);
    bf16x2 nhr = LD2(ghn, 0), nhz = LD2(ghn, 256), nhn = LD2(ghn, 512);
    float2 ebr = BI2(ebih, 0), ebz = BI2(ebih, 256), ebn = BI2(ebih, 512);
    float2 eb2r = BI2(ebhh, 0), eb2z = BI2(ebhh, 256), eb2n = BI2(ebhh, 512);
    float2 nbr = BI2(nbih, 0), nbz = BI2(nbih, 256), nbn = BI2(nbih, 512);
    float2 nb2r = BI2(nbhh, 0), nb2z = BI2(nbhh, 256), nb2n = BI2(nbhh, 512);
#undef LD2
#undef BI2

    float res[2];
#pragma unroll
    for (int j = 0; j < 2; j++) {
        float hj = j == 0 ? hv.x : hv.y;
        float r = sigm(((float)eir[j] + (j ? ebr.y : ebr.x)) + ((float)ehr[j] + (j ? eb2r.y : eb2r.x)));
        float z = sigm(((float)eiz[j] + (j ? ebz.y : ebz.x)) + ((float)ehz[j] + (j ? eb2z.y : eb2z.x)));
        float nv = tanhf(((float)ein[j] + (j ? ebn.y : ebn.x)) + r * ((float)ehn[j] + (j ? eb2n.y : eb2n.x)));
        float eo = (1.f - z) * nv + z * hj;
        float r2 = sigm(((float)nir[j] + (j ? nbr.y : nbr.x)) + ((float)nhr[j] + (j ? nb2r.y : nb2r.x)));
        float z2 = sigm(((float)niz[j] + (j ? nbz.y : nbz.x)) + ((float)nhz[j] + (j ? nb2z.y : nb2z.x)));
        float nv2 = tanhf(((float)nin[j] + (j ? nbn.y : nbn.x)) + r2 * ((float)nhn[j] + (j ? nb2n.y : nb2n.x)));
        float no = (1.f - z2) * nv2 + z2 * hj;
        res[j] = De * eo + Dn * no;
    }
    *(float2*)(out + (size_t)i * HH + c) = make_float2(res[0], res[1]);
}

extern "C" void kernel_launch(void* const* d_in, const int* in_sizes, int n_in,
                              void* d_out, int out_size, void* d_ws, size_t ws_size,
                              hipStream_t stream) {
    const float* h        = (const float*)d_in[0];
    const float* node_adj = (const float*)d_in[1];
    const float* edge_adj = (const float*)d_in[2];
    const float* gat_W    = (const float*)d_in[3];
    const float* gat_a    = (const float*)d_in[4];
    const float* e_Wih    = (const float*)d_in[5];
    const float* e_Whh    = (const float*)d_in[6];
    const float* e_bih    = (const float*)d_in[7];
    const float* e_bhh    = (const float*)d_in[8];
    const float* n_Wih    = (const float*)d_in[9];
    const float* n_Whh    = (const float*)d_in[10];
    const float* n_bih    = (const float*)d_in[11];
    const float* n_bhh    = (const float*)d_in[12];
    float* out = (float*)d_out;

    char* ws = (char*)d_ws;
    size_t off = 0;
    auto alloc = [&](size_t bytes) { char* p = ws + off; off += (bytes + 255) & ~(size_t)255; return p; };

    float* ep    = (float*)alloc((size_t)NHEADS * NN * 4);
    float* em    = (float*)alloc((size_t)NHEADS * NN * 4);
    float* c0    = (float*)alloc((size_t)NHEADS * HH * 4);
    float* c1    = (float*)alloc((size_t)NHEADS * HH * 4);
    float* dn    = (float*)alloc(NN * 4);
    float* de    = (float*)alloc(NN * 4);
    bf16*  hb    = (bf16*)alloc((size_t)NN * HH * 2);
    bf16*  nsupb = (bf16*)alloc((size_t)NN * HH * 2);
    bf16*  esupb = (bf16*)alloc((size_t)NN * HH * 2);
    bf16*  hWb2  = (bf16*)alloc((size_t)NN * G3 * 2);
    bf16*  gie   = (bf16*)alloc((size_t)NN * G3 * 2);
    bf16*  ghe   = (bf16*)alloc((size_t)NN * G3 * 2);
    bf16*  gin   = (bf16*)alloc((size_t)NN * G3 * 2);
    bf16*  ghn   = (bf16*)alloc((size_t)NN * G3 * 2);
    bf16*  Weib  = (bf16*)alloc((size_t)G3 * HH * 2);
    bf16*  Wehb  = (bf16*)alloc((size_t)G3 * HH * 2);
    bf16*  Wnib  = (bf16*)alloc((size_t)G3 * HH * 2);
    bf16*  Wnhb  = (bf16*)alloc((size_t)G3 * HH * 2);
    bf16*  Wtb   = (bf16*)alloc((size_t)NHEADS * HH * HH * 2);
    int*   ccols_n = (int*)alloc((size_t)NN * MAXE * 4);
    int*   nnz_n   = (int*)alloc(NN * 4);
    int*   ccols_e = (int*)alloc((size_t)NN * MAXE * 4);
    int*   nnz_e   = (int*)alloc(NN * 4);

    dim3 b256(256);

    // 1. pure streaming compaction of both adjacency matrices
    compact_k<<<2 * NN, b256, 0, stream>>>(node_adj, edge_adj, dn, de,
                                           ccols_n, nnz_n, ccols_e, nnz_e);

    // 2. prep: converts + gat_W transpose + gat_c
    prep_k<<<1987, b256, 0, stream>>>(h, e_Wih, e_Whh, n_Wih, n_Whh, gat_W, gat_a,
                                      hb, Weib, Wehb, Wnib, Wnhb, Wtb, c0, c1);

    // 3. node gather: nsup + gat_e
    gather_k<<<NN, b256, 0, stream>>>(ccols_n, nnz_n, hb, c0, c1, nsupb, ep, em);

    // 4. gemmA z=3: hW (3 heads concat N=768), gi_e, gh_e
    gemm_bt<<<dim3(NN / 128, G3 / 128, 3), b256, 0, stream>>>(
        hb, nsupb, hb, Wtb, Weib, Wehb, hWb2, gie, ghe);

    // 5. GAT sparse attention output
    gat_out<<<NN, b256, 0, stream>>>(ccols_e, nnz_e, ep, em, hWb2, esupb);

    // 6. gemmB z=2: gi_n, gh_n
    gemm_bt<<<dim3(NN / 128, G3 / 128, 2), b256, 0, stream>>>(
        esupb, hb, hb, Wnib, Wnhb, Wnhb, gin, ghn, ghn);

    // 7. both GRUs + combine -> out
    gru_both<<<NN / 2, b256, 0, stream>>>(gie, ghe, gin, ghn,
                                          e_bih, e_bhh, n_bih, n_bhh,
                                          h, dn, de, out);
}

// Round 9
// 92.866 us; speedup vs baseline: 1.0902x; 1.0276x over previous
//
#include <hip/hip_runtime.h>
#include <hip/hip_bf16.h>
#include <math.h>

#define NN 4096
#define HH 256
#define G3 768
#define NHEADS 3
#define MAXE 128
#define ALPHA 0.2f

typedef __bf16 bf16;
typedef __attribute__((ext_vector_type(2))) __bf16 bf16x2;
typedef __attribute__((ext_vector_type(4))) __bf16 bf16x4;
typedef __attribute__((ext_vector_type(8))) __bf16 bf16x8;
typedef __attribute__((ext_vector_type(4))) float f32x4;

__device__ __forceinline__ void async_copy16(void* lds, const void* g) {
    __builtin_amdgcn_global_load_lds((const __attribute__((address_space(1))) void*)g,
                                     (__attribute__((address_space(3))) void*)lds, 16, 0, 0);
}

__device__ inline float lrelu(float x) { return x > 0.f ? x : ALPHA * x; }
__device__ inline float sigm(float x) { return 1.f / (1.f + __expf(-x)); }

// ================= prep: all converts + transposes + gat_c in one kernel =================
__global__ __launch_bounds__(256) void prep_k(
    const float* __restrict__ h,
    const float* __restrict__ eWih, const float* __restrict__ eWhh,
    const float* __restrict__ nWih, const float* __restrict__ nWhh,
    const float* __restrict__ gat_W, const float* __restrict__ gat_a,
    bf16* __restrict__ hb,
    bf16* __restrict__ Weib, bf16* __restrict__ Wehb,
    bf16* __restrict__ Wnib, bf16* __restrict__ Wnhb,
    bf16* __restrict__ Wtb, float* __restrict__ c0, float* __restrict__ c1) {
    __shared__ float tile[32][33];
    __shared__ float a_s[512];
    int b = blockIdx.x, t = threadIdx.x;
    if (b < 1024) {
        int idx = b * 256 + t;
        float4 v = *(const float4*)(h + (size_t)idx * 4);
        bf16x4 o = {(bf16)v.x, (bf16)v.y, (bf16)v.z, (bf16)v.w};
        *(bf16x4*)(hb + (size_t)idx * 4) = o;
    } else if (b < 1792) {
        int w = (b - 1024) / 192;
        int idx = ((b - 1024) % 192) * 256 + t;
        const float* in = w == 0 ? eWih : (w == 1 ? eWhh : (w == 2 ? nWih : nWhh));
        bf16* outp = w == 0 ? Weib : (w == 1 ? Wehb : (w == 2 ? Wnib : Wnhb));
        float4 v = *(const float4*)(in + (size_t)idx * 4);
        bf16x4 o = {(bf16)v.x, (bf16)v.y, (bf16)v.z, (bf16)v.w};
        *(bf16x4*)(outp + (size_t)idx * 4) = o;
    } else if (b < 1984) {
        int b2 = b - 1792;
        int hd = b2 >> 6, tl = b2 & 63;
        int k0 = (tl >> 3) * 32, n0 = (tl & 7) * 32;
        int tx = t % 32, ty = t / 32;
        const float* Wh = gat_W + (size_t)hd * HH * HH;
        for (int r = ty; r < 32; r += 8) tile[r][tx] = Wh[(size_t)(k0 + r) * HH + n0 + tx];
        __syncthreads();
        bf16* Wth = Wtb + (size_t)hd * HH * HH;
        for (int r = ty; r < 32; r += 8) Wth[(size_t)(n0 + r) * HH + k0 + tx] = (bf16)tile[tx][r];
    } else {
        int hd = b - 1984;
        a_s[t] = gat_a[(size_t)hd * 512 + t];
        a_s[t + 256] = gat_a[(size_t)hd * 512 + 256 + t];
        __syncthreads();
        const float* Wr = gat_W + (size_t)hd * HH * HH + (size_t)t * HH;
        f32x4 s0v = {}, s1v = {};
#pragma unroll 8
        for (int c4 = 0; c4 < 64; c4++) {
            f32x4 w = *(const f32x4*)(Wr + c4 * 4);
            f32x4 a0 = *(const f32x4*)(a_s + c4 * 4);
            f32x4 a1 = *(const f32x4*)(a_s + 256 + c4 * 4);
            s0v += w * a0;
            s1v += w * a1;
        }
        c0[hd * HH + t] = s0v[0] + s0v[1] + s0v[2] + s0v[3];
        c1[hd * HH + t] = s1v[0] + s1v[1] + s1v[2] + s1v[3];
    }
}

// ================= mega: 3-slice GEMM (hb-only deps) CONCURRENT with adjacency compaction ==
// bid < 576: gemm {hW, ghe, ghn} = hb @ {Wtb, Wehb, Wnhb}^T (z = bid/192).
// bid >= 576: compaction of one row of node/edge adjacency. XCD-contiguous row swizzle:
// g2=(bid-576); gs=(g2&7)*1024+(g2>>3) so each XCD streams a contiguous 16 MB region.
#define NGEMM 576
__global__ __launch_bounds__(256) void mega_k(
    const float* __restrict__ node_adj, const float* __restrict__ edge_adj,
    float* __restrict__ dn, float* __restrict__ de,
    int* __restrict__ ccols_n, int* __restrict__ nnz_n,
    int* __restrict__ ccols_e, int* __restrict__ nnz_e,
    const bf16* __restrict__ hb, const bf16* __restrict__ Wtb,
    const bf16* __restrict__ Wehb, const bf16* __restrict__ Wnhb,
    bf16* __restrict__ hWb2, bf16* __restrict__ ghe, bf16* __restrict__ ghn) {
    __shared__ bf16 a_s[128 * 32];
    __shared__ bf16 b_s[128 * 32];
    __shared__ int cnt;
    __shared__ int cols_s[MAXE];
    int bid = blockIdx.x, t = threadIdx.x;

    if (bid < NGEMM) {
        // ---------------- GEMM role ----------------
        int z = bid / 192, r = bid % 192;
        int i0 = (r % 32) * 128;
        int c0n = (r / 32) * 128;
        const bf16* Bt = z == 0 ? Wtb : (z == 1 ? Wehb : Wnhb);
        bf16* C = z == 0 ? hWb2 : (z == 1 ? ghe : ghn);

        int lane = t & 63, wid = t >> 6;
        int wr = (wid >> 1) * 64, wc = (wid & 1) * 64;
        f32x4 acc[4][4] = {};
        int kq = (lane >> 4) * 8;

        for (int k0 = 0; k0 < 256; k0 += 32) {
            __syncthreads();
#pragma unroll
            for (int it = 0; it < 2; it++) {
                int ch = it * 256 + t;
                int rr = ch >> 2, c16 = ch & 3;
                async_copy16(&a_s[ch * 8], hb + (size_t)(i0 + rr) * 256 + k0 + c16 * 8);
                async_copy16(&b_s[ch * 8], Bt + (size_t)(c0n + rr) * 256 + k0 + c16 * 8);
            }
            __syncthreads();
            bf16x8 af[4], bf[4];
#pragma unroll
            for (int m = 0; m < 4; m++) af[m] = *(const bf16x8*)&a_s[(wr + m * 16 + (lane & 15)) * 32 + kq];
#pragma unroll
            for (int n = 0; n < 4; n++) bf[n] = *(const bf16x8*)&b_s[(wc + n * 16 + (lane & 15)) * 32 + kq];
#pragma unroll
            for (int m = 0; m < 4; m++)
#pragma unroll
                for (int n = 0; n < 4; n++)
                    acc[m][n] = __builtin_amdgcn_mfma_f32_16x16x32_bf16(af[m], bf[n], acc[m][n], 0, 0, 0);
        }
#pragma unroll
        for (int m = 0; m < 4; m++) {
#pragma unroll
            for (int n = 0; n < 4; n++) {
                int row = i0 + wr + m * 16 + (lane >> 4) * 4;
                int col = c0n + wc + n * 16 + (lane & 15);
#pragma unroll
                for (int j = 0; j < 4; j++)
                    C[(size_t)(row + j) * G3 + col] = (bf16)acc[m][n][j];
            }
        }
    } else {
        // ---------------- compaction role ----------------
        int g2 = bid - NGEMM;
        int gs = (g2 & 7) * 1024 + (g2 >> 3);   // XCD-contiguous streams
        bool node = gs < NN;
        int i = node ? gs : gs - NN;
        if (t == 0) cnt = 0;
        __syncthreads();
        const float* rp = (node ? node_adj : edge_adj) + (size_t)i * NN + t * 16;

        f32x4 v0 = *(const f32x4*)(rp);
        f32x4 v1 = *(const f32x4*)(rp + 4);
        f32x4 v2 = *(const f32x4*)(rp + 8);
        f32x4 v3 = *(const f32x4*)(rp + 12);
        int j0 = t * 16;

        int k = 0;
#define CNT(A, J) { float a_ = (A); if (a_ != 0.f) { if ((J) == i) (node ? dn : de)[i] = a_; else k++; } }
        CNT(v0[0], j0)      CNT(v0[1], j0 + 1)  CNT(v0[2], j0 + 2)  CNT(v0[3], j0 + 3)
        CNT(v1[0], j0 + 4)  CNT(v1[1], j0 + 5)  CNT(v1[2], j0 + 6)  CNT(v1[3], j0 + 7)
        CNT(v2[0], j0 + 8)  CNT(v2[1], j0 + 9)  CNT(v2[2], j0 + 10) CNT(v2[3], j0 + 11)
        CNT(v3[0], j0 + 12) CNT(v3[1], j0 + 13) CNT(v3[2], j0 + 14) CNT(v3[3], j0 + 15)
#undef CNT
        int base = 0;
        if (k) base = atomicAdd(&cnt, k);
#define WRT(A, J) { float a_ = (A); if (a_ != 0.f && (J) != i) { \
            if (base < MAXE) cols_s[base] = (a_ > 0.f) ? ((J) + 1) : -((J) + 1); base++; } }
        WRT(v0[0], j0)      WRT(v0[1], j0 + 1)  WRT(v0[2], j0 + 2)  WRT(v0[3], j0 + 3)
        WRT(v1[0], j0 + 4)  WRT(v1[1], j0 + 5)  WRT(v1[2], j0 + 6)  WRT(v1[3], j0 + 7)
        WRT(v2[0], j0 + 8)  WRT(v2[1], j0 + 9)  WRT(v2[2], j0 + 10) WRT(v2[3], j0 + 11)
        WRT(v3[0], j0 + 12) WRT(v3[1], j0 + 13) WRT(v3[2], j0 + 14) WRT(v3[3], j0 + 15)
#undef WRT
        __syncthreads();
        int n = cnt < MAXE ? cnt : MAXE;
        int* cg = (node ? ccols_n : ccols_e) + (size_t)i * MAXE;
        if (t == 0) (node ? nnz_n : nnz_e)[i] = n;
        if (t < n) cg[t] = cols_s[t];
    }
}

// ================= node gather: nsup + fused gat_e (reads node CSR) =================
__global__ __launch_bounds__(256) void gather_k(
    const int* __restrict__ ccols_n, const int* __restrict__ nnz_n,
    const bf16* __restrict__ hb,
    const float* __restrict__ c0, const float* __restrict__ c1,
    bf16* __restrict__ nsupb, float* __restrict__ ep, float* __restrict__ em) {
    int i = blockIdx.x, t = threadIdx.x, lane = t & 63, wid = t >> 6;
    __shared__ int cols_s[MAXE];
    __shared__ float part[6][4];
    int n = nnz_n[i];
    if (n > MAXE) n = MAXE;
    if (t < n) cols_s[t] = ccols_n[(size_t)i * MAXE + t];
    __syncthreads();
    float accp = 0.f, accm = 0.f;
#pragma unroll 8
    for (int kk = 0; kk < n; kk++) {
        int c = cols_s[kk];  // LDS broadcast
        int j = (c > 0 ? c : -c) - 1;
        float hv = (float)hb[(size_t)j * HH + t];
        if (c > 0) accp += hv; else accm += hv;
    }
    nsupb[(size_t)i * HH + t] = (bf16)(accp - accm);
    float u[6];
#pragma unroll
    for (int hd = 0; hd < NHEADS; hd++) {
        float a0 = c0[hd * HH + t], a1 = c1[hd * HH + t];
        u[hd * 2]     = accp * a0 + accm * a1;
        u[hd * 2 + 1] = accm * a0 + accp * a1;
    }
#pragma unroll
    for (int vv = 0; vv < 6; vv++)
#pragma unroll
        for (int off = 32; off; off >>= 1) u[vv] += __shfl_xor(u[vv], off);
    if (lane == 0)
#pragma unroll
        for (int vv = 0; vv < 6; vv++) part[vv][wid] = u[vv];
    __syncthreads();
    if (t < 6) {
        float s = part[t][0] + part[t][1] + part[t][2] + part[t][3];
        int hd = t >> 1;
        ((t & 1) == 0 ? ep : em)[(size_t)hd * NN + i] = lrelu(s);
    }
}

// ================= bf16 MFMA GEMM (m97 structure), z-batched up to 3 =================
__global__ __launch_bounds__(256) void gemm_bt(
    const bf16* __restrict__ A0, const bf16* __restrict__ A1, const bf16* __restrict__ A2,
    const bf16* __restrict__ B0, const bf16* __restrict__ B1, const bf16* __restrict__ B2,
    bf16* __restrict__ C0, bf16* __restrict__ C1, bf16* __restrict__ C2) {
    __shared__ bf16 a_s[128 * 32];
    __shared__ bf16 b_s[128 * 32];
    int z = blockIdx.z;
    const bf16* A = z == 0 ? A0 : (z == 1 ? A1 : A2);
    const bf16* Bt = z == 0 ? B0 : (z == 1 ? B1 : B2);
    bf16* C = z == 0 ? C0 : (z == 1 ? C1 : C2);

    int tid = threadIdx.x;
    int lane = tid & 63, wid = tid >> 6;
    int wr = (wid >> 1) * 64, wc = (wid & 1) * 64;
    int i0 = blockIdx.x * 128;
    int c0n = blockIdx.y * 128;

    f32x4 acc[4][4] = {};
    int kq = (lane >> 4) * 8;

    for (int k0 = 0; k0 < 256; k0 += 32) {
        __syncthreads();
#pragma unroll
        for (int it = 0; it < 2; it++) {
            int ch = it * 256 + tid;
            int r = ch >> 2, c16 = ch & 3;
            async_copy16(&a_s[ch * 8], A + (size_t)(i0 + r) * 256 + k0 + c16 * 8);
            async_copy16(&b_s[ch * 8], Bt + (size_t)(c0n + r) * 256 + k0 + c16 * 8);
        }
        __syncthreads();
        bf16x8 af[4], bf[4];
#pragma unroll
        for (int m = 0; m < 4; m++) af[m] = *(const bf16x8*)&a_s[(wr + m * 16 + (lane & 15)) * 32 + kq];
#pragma unroll
        for (int n = 0; n < 4; n++) bf[n] = *(const bf16x8*)&b_s[(wc + n * 16 + (lane & 15)) * 32 + kq];
#pragma unroll
        for (int m = 0; m < 4; m++)
#pragma unroll
            for (int n = 0; n < 4; n++)
                acc[m][n] = __builtin_amdgcn_mfma_f32_16x16x32_bf16(af[m], bf[n], acc[m][n], 0, 0, 0);
    }
#pragma unroll
    for (int m = 0; m < 4; m++) {
#pragma unroll
        for (int n = 0; n < 4; n++) {
            int row = i0 + wr + m * 16 + (lane >> 4) * 4;
            int col = c0n + wc + n * 16 + (lane & 15);
#pragma unroll
            for (int j = 0; j < 4; j++)
                C[(size_t)(row + j) * G3 + col] = (bf16)acc[m][n][j];
        }
    }
}

// ================= GAT sparse output =================
__global__ __launch_bounds__(256) void gat_out(
    const int* __restrict__ ccols_e, const int* __restrict__ nnz_e,
    const float* __restrict__ ep, const float* __restrict__ em,
    const bf16* __restrict__ hWb2, bf16* __restrict__ esupb) {
    int i = blockIdx.x, t = threadIdx.x;
    __shared__ int cols_s[MAXE];
    __shared__ int js[MAXE];
    __shared__ float w_s[NHEADS][MAXE];
    __shared__ f32x4 sacc[NHEADS][64];
    int n = nnz_e[i];
    if (n > MAXE) n = MAXE;
    if (t < n) {
        int c = ccols_e[(size_t)i * MAXE + t];
        cols_s[t] = c;
        js[t] = (c > 0 ? c : -c) - 1;
    }
    __syncthreads();
    int wid = t >> 6, lane = t & 63;
    if (wid < NHEADS) {
        int hd = wid;
        const float* eph = ep + (size_t)hd * NN;
        const float* emh = em + (size_t)hd * NN;
        float v0 = -1e30f, v1 = -1e30f;
        if (lane < n)      { int c = cols_s[lane];      v0 = c > 0 ? eph[js[lane]]      : emh[js[lane]]; }
        if (lane + 64 < n) { int c = cols_s[lane + 64]; v1 = c > 0 ? eph[js[lane + 64]] : emh[js[lane + 64]]; }
        float mx = fmaxf(v0, v1);
#pragma unroll
        for (int off = 32; off; off >>= 1) mx = fmaxf(mx, __shfl_xor(mx, off));
        float w0 = (lane < n) ? __expf(v0 - mx) : 0.f;
        float w1 = (lane + 64 < n) ? __expf(v1 - mx) : 0.f;
        float s = w0 + w1;
#pragma unroll
        for (int off = 32; off; off >>= 1) s += __shfl_xor(s, off);
        float inv = 1.f / s;
        if (lane < n)      w_s[hd][lane]      = (cols_s[lane] > 0 ? w0 : -w0) * inv;
        if (lane + 64 < n) w_s[hd][lane + 64] = (cols_s[lane + 64] > 0 ? w1 : -w1) * inv;
    }
    __syncthreads();
    if (t < 192) {
        int hd = t >> 6, g = t & 63;
        const bf16* base = hWb2 + (size_t)hd * HH + g * 4;
        f32x4 acc = {};
#pragma unroll 4
        for (int k = 0; k < n; k++) {
            float w = w_s[hd][k];
            bf16x4 hv = *(const bf16x4*)(base + (size_t)js[k] * G3);
            f32x4 f = {(float)hv[0], (float)hv[1], (float)hv[2], (float)hv[3]};
            acc += w * f;
        }
        sacc[hd][g] = acc;
    }
    __syncthreads();
    if (t < 64) {
        f32x4 s = (sacc[0][t] + sacc[1][t] + sacc[2][t]) * (1.f / 3.f);
        bf16x4 o = {(bf16)s[0], (bf16)s[1], (bf16)s[2], (bf16)s[3]};
        *(bf16x4*)(esupb + (size_t)i * HH + t * 4) = o;
    }
}

// ================= both GRU cells + final combine, writes d_out =================
__global__ __launch_bounds__(256) void gru_both(
    const bf16* __restrict__ gie, const bf16* __restrict__ ghe,
    const bf16* __restrict__ gin, const bf16* __restrict__ ghn,
    const float* __restrict__ ebih, const float* __restrict__ ebhh,
    const float* __restrict__ nbih, const float* __restrict__ nbhh,
    const float* __restrict__ h, const float* __restrict__ dnv, const float* __restrict__ dev,
    float* __restrict__ out) {
    int sub = threadIdx.x >> 7, tc = threadIdx.x & 127;
    int i = blockIdx.x * 2 + sub;
    int c = tc * 2;
    size_t gb = (size_t)i * G3;
    float2 hv = *(const float2*)(h + (size_t)i * HH + c);
    float De = dev[i], Dn = dnv[i];

#define LD2(p, off) (*(const bf16x2*)((p) + gb + (off) + c))
#define BI2(p, off) (*(const float2*)((p) + (off) + c))
    bf16x2 eir = LD2(gie, 0), eiz = LD2(gie, 256), ein = LD2(gie, 512);
    bf16x2 ehr = LD2(ghe, 0), ehz = LD2(ghe, 256), ehn = LD2(ghe, 512);
    bf16x2 nir = LD2(gin, 0), niz = LD2(gin, 256), nin = LD2(gin, 512);
    bf16x2 nhr = LD2(ghn, 0), nhz = LD2(ghn, 256), nhn = LD2(ghn, 512);
    float2 ebr = BI2(ebih, 0), ebz = BI2(ebih, 256), ebn = BI2(ebih, 512);
    float2 eb2r = BI2(ebhh, 0), eb2z = BI2(ebhh, 256), eb2n = BI2(ebhh, 512);
    float2 nbr = BI2(nbih, 0), nbz = BI2(nbih, 256), nbn = BI2(nbih, 512);
    float2 nb2r = BI2(nbhh, 0), nb2z = BI2(nbhh, 256), nb2n = BI2(nbhh, 512);
#undef LD2
#undef BI2

    float res[2];
#pragma unroll
    for (int j = 0; j < 2; j++) {
        float hj = j == 0 ? hv.x : hv.y;
        float r = sigm(((float)eir[j] + (j ? ebr.y : ebr.x)) + ((float)ehr[j] + (j ? eb2r.y : eb2r.x)));
        float z = sigm(((float)eiz[j] + (j ? ebz.y : ebz.x)) + ((float)ehz[j] + (j ? eb2z.y : eb2z.x)));
        float nv = tanhf(((float)ein[j] + (j ? ebn.y : ebn.x)) + r * ((float)ehn[j] + (j ? eb2n.y : eb2n.x)));
        float eo = (1.f - z) * nv + z * hj;
        float r2 = sigm(((float)nir[j] + (j ? nbr.y : nbr.x)) + ((float)nhr[j] + (j ? nb2r.y : nb2r.x)));
        float z2 = sigm(((float)niz[j] + (j ? nbz.y : nbz.x)) + ((float)nhz[j] + (j ? nb2z.y : nb2z.x)));
        float nv2 = tanhf(((float)nin[j] + (j ? nbn.y : nbn.x)) + r2 * ((float)nhn[j] + (j ? nb2n.y : nb2n.x)));
        float no = (1.f - z2) * nv2 + z2 * hj;
        res[j] = De * eo + Dn * no;
    }
    *(float2*)(out + (size_t)i * HH + c) = make_float2(res[0], res[1]);
}

extern "C" void kernel_launch(void* const* d_in, const int* in_sizes, int n_in,
                              void* d_out, int out_size, void* d_ws, size_t ws_size,
                              hipStream_t stream) {
    const float* h        = (const float*)d_in[0];
    const float* node_adj = (const float*)d_in[1];
    const float* edge_adj = (const float*)d_in[2];
    const float* gat_W    = (const float*)d_in[3];
    const float* gat_a    = (const float*)d_in[4];
    const float* e_Wih    = (const float*)d_in[5];
    const float* e_Whh    = (const float*)d_in[6];
    const float* e_bih    = (const float*)d_in[7];
    const float* e_bhh    = (const float*)d_in[8];
    const float* n_Wih    = (const float*)d_in[9];
    const float* n_Whh    = (const float*)d_in[10];
    const float* n_bih    = (const float*)d_in[11];
    const float* n_bhh    = (const float*)d_in[12];
    float* out = (float*)d_out;

    char* ws = (char*)d_ws;
    size_t off = 0;
    auto alloc = [&](size_t bytes) { char* p = ws + off; off += (bytes + 255) & ~(size_t)255; return p; };

    float* ep    = (float*)alloc((size_t)NHEADS * NN * 4);
    float* em    = (float*)alloc((size_t)NHEADS * NN * 4);
    float* c0    = (float*)alloc((size_t)NHEADS * HH * 4);
    float* c1    = (float*)alloc((size_t)NHEADS * HH * 4);
    float* dn    = (float*)alloc(NN * 4);
    float* de    = (float*)alloc(NN * 4);
    bf16*  hb    = (bf16*)alloc((size_t)NN * HH * 2);
    bf16*  nsupb = (bf16*)alloc((size_t)NN * HH * 2);
    bf16*  esupb = (bf16*)alloc((size_t)NN * HH * 2);
    bf16*  hWb2  = (bf16*)alloc((size_t)NN * G3 * 2);
    bf16*  gie   = (bf16*)alloc((size_t)NN * G3 * 2);
    bf16*  ghe   = (bf16*)alloc((size_t)NN * G3 * 2);
    bf16*  gin   = (bf16*)alloc((size_t)NN * G3 * 2);
    bf16*  ghn   = (bf16*)alloc((size_t)NN * G3 * 2);
    bf16*  Weib  = (bf16*)alloc((size_t)G3 * HH * 2);
    bf16*  Wehb  = (bf16*)alloc((size_t)G3 * HH * 2);
    bf16*  Wnib  = (bf16*)alloc((size_t)G3 * HH * 2);
    bf16*  Wnhb  = (bf16*)alloc((size_t)G3 * HH * 2);
    bf16*  Wtb   = (bf16*)alloc((size_t)NHEADS * HH * HH * 2);
    int*   ccols_n = (int*)alloc((size_t)NN * MAXE * 4);
    int*   nnz_n   = (int*)alloc(NN * 4);
    int*   ccols_e = (int*)alloc((size_t)NN * MAXE * 4);
    int*   nnz_e   = (int*)alloc(NN * 4);

    dim3 b256(256);

    // 1. prep: converts + gat_W transpose + gat_c (everything mega's gemm role needs)
    prep_k<<<1987, b256, 0, stream>>>(h, e_Wih, e_Whh, n_Wih, n_Whh, gat_W, gat_a,
                                      hb, Weib, Wehb, Wnib, Wnhb, Wtb, c0, c1);

    // 2. mega: gemm{hW, ghe, ghn} (hb-only deps) runs concurrently with both compactions
    mega_k<<<NGEMM + 2 * NN, b256, 0, stream>>>(node_adj, edge_adj, dn, de,
                                                ccols_n, nnz_n, ccols_e, nnz_e,
                                                hb, Wtb, Wehb, Wnhb, hWb2, ghe, ghn);

    // 3. node gather: nsup + gat_e
    gather_k<<<NN, b256, 0, stream>>>(ccols_n, nnz_n, hb, c0, c1, nsupb, ep, em);

    // 4. GAT sparse attention output
    gat_out<<<NN, b256, 0, stream>>>(ccols_e, nnz_e, ep, em, hWb2, esupb);

    // 5. gemm z=2: gie, gin
    gemm_bt<<<dim3(NN / 128, G3 / 128, 2), b256, 0, stream>>>(
        nsupb, esupb, esupb, Weib, Wnib, Wnib, gie, gin, gin);

    // 6. both GRUs + combine -> out
    gru_both<<<NN / 2, b256, 0, stream>>>(gie, ghe, gin, ghn,
                                          e_bih, e_bhh, n_bih, n_bhh,
                                          h, dn, de, out);
}